// Round 6
// baseline (5146.750 us; speedup 1.0000x reference)
//
#include <hip/hip_runtime.h>
#include <hip/hip_cooperative_groups.h>
#include <stdint.h>

namespace cg = cooperative_groups;

#define D_ 1024
#define H_ 16
#define HD_ 64
#define FF_ 4096
#define T_ 4096
#define TC_ 4097
#define CHUNK_ 64
#define NCH_ 65
#define LAYERS_ 8
#define NB_ 1024

// ws layout (floats)
#define WS_QKV 0          // [3072]
#define WS_GU 3072        // [8192]
#define WS_HID 11264      // [1024]
#define WS_PART 12288     // [16*65*66 = 68640]

static constexpr float SCALE_ = 0.49497474683058327f; // 1.4/sqrt(8)
static constexpr float EPS_ = 1e-5f;

struct Params {
    const float* kc[LAYERS_];
    const float* vc[LAYERS_];
    const float* embed; const float* ln1; const float* ln2; const float* nw;
    const float* Wq; const float* Wk; const float* Wv; const float* Wo;
    const float* Wg; const float* Wu; const float* Wd;
    const int* pos;
    float* out;
    float* accQKV; float* accGU; float* hid; float* part;
};

__device__ __forceinline__ float wave_sum(float v) {
    #pragma unroll
    for (int off = 32; off; off >>= 1) v += __shfl_down(v, off, 64);
    return v;
}
__device__ __forceinline__ float wave_max(float v) {
    #pragma unroll
    for (int off = 32; off; off >>= 1) v = fmaxf(v, __shfl_down(v, off, 64));
    return v;
}

// rms(hid)*lnw -> hn[1024]; wred = 4-float scratch. All 256 threads.
__device__ __forceinline__ void rms_to_sm(const float* __restrict__ hid,
                                          const float* __restrict__ lnw,
                                          float* hn, float* wred, int t)
{
    float4 hv = ((const float4*)hid)[t];
    float ssq = hv.x*hv.x + hv.y*hv.y + hv.z*hv.z + hv.w*hv.w;
    ssq = wave_sum(ssq);
    if ((t & 63) == 0) wred[t >> 6] = ssq;
    __syncthreads();
    float rms = rsqrtf((wred[0] + wred[1] + wred[2] + wred[3]) * (1.0f / D_) + EPS_);
    float4 lw = ((const float4*)lnw)[t];
    hn[4*t+0] = hv.x * rms * lw.x;
    hn[4*t+1] = hv.y * rms * lw.y;
    hn[4*t+2] = hv.z * rms * lw.z;
    hn[4*t+3] = hv.w * rms * lw.w;
    __syncthreads();
}

// RT-row x 64-col gemv tile: dst[colbase + 0..64) += scale * (hsrc[rows] @ W-tile)
template<int RT>
__device__ __forceinline__ void gemv_tile(const float* __restrict__ hsrc,
                                          const float* __restrict__ W, int ncols,
                                          int rowbase, int colbase, float scale,
                                          float* __restrict__ dst, float4* red4, int t)
{
    constexpr int RPG = RT / 16;
    int c4 = t & 15, rg = t >> 4;
    int row0 = rowbase + rg * RPG;
    const float* Wp = W + (size_t)row0 * ncols + colbase + c4 * 4;
    float4 acc = make_float4(0.f, 0.f, 0.f, 0.f);
    #pragma unroll
    for (int r = 0; r < RPG; ++r) {
        float hs = hsrc[row0 + r];
        float4 w4 = *(const float4*)(Wp + (size_t)r * ncols);
        acc.x += hs*w4.x; acc.y += hs*w4.y; acc.z += hs*w4.z; acc.w += hs*w4.w;
    }
    red4[t] = acc;
    __syncthreads();
    if (t < 16) {
        float4 s = red4[t];
        #pragma unroll
        for (int g = 1; g < 16; ++g) {
            float4 r4 = red4[t + 16*g];
            s.x += r4.x; s.y += r4.y; s.z += r4.z; s.w += r4.w;
        }
        float* d = dst + colbase + t*4;
        atomicAdd(d+0, scale*s.x);
        atomicAdd(d+1, scale*s.y);
        atomicAdd(d+2, scale*s.z);
        atomicAdd(d+3, scale*s.w);
    }
    __syncthreads();
}

__launch_bounds__(256, 4)
__global__ void k_model(Params p)
{
    cg::grid_group grid = cg::this_grid();
    int t = threadIdx.x;
    int b = blockIdx.x;
    __shared__ float sm[2080];       // 8.3 KB
    float* hn   = sm;                // [1024] (gemv phases)
    float4* red4 = (float4*)(sm + 1024); // [256] float4
    float* wred = sm + 2048;         // [4]

    // ---- init: hid = embed; zero accumulators ----
    if (b == 0)      ((float4*)p.hid)[t] = ((const float4*)p.embed)[t];
    else if (b == 1) for (int i = t; i < 3072; i += 256) p.accQKV[i] = 0.f;
    else if (b == 2) for (int i = t; i < 2*FF_; i += 256) p.accGU[i] = 0.f;
    grid.sync();

    for (int L = 0; L < LAYERS_; ++L) {
        // ======== phase 1: QKV gemv (3 x 16 rowtiles(64) x 16 coltiles = 768 tiles) ========
        rms_to_sm(p.hid, p.ln1 + L*D_, hn, wred, t);
        for (int tau = b; tau < 768; tau += NB_) {
            int mat = tau >> 8, rem = tau & 255, rt = rem >> 4, ct = rem & 15;
            const float* W = (mat == 0 ? p.Wq : mat == 1 ? p.Wk : p.Wv) + (size_t)L*D_*D_;
            gemv_tile<64>(hn, W, D_, rt*64, ct*64, 1.f, p.accQKV + mat*D_, red4, t);
        }
        grid.sync();

        // ======== phase 2: attention chunks (65 x 16 = 1040 tiles) + f32 KV copy-out ========
        {
            float* qr = sm;        // [64]
            float* kr = sm + 64;   // [64]
            float* sc = sm + 128;  // [65]
            float* wr2 = sm + 200; // [8]
            float* red = sm + 256; // [256]
            const float* kcache = p.kc[L];
            const float* vcache = p.vc[L];
            float* kco = p.out + 1024 + (size_t)L * 2 * ((size_t)H_*TC_*HD_);
            float* vco = kco + (size_t)H_*TC_*HD_;
            for (int tau = b; tau < NCH_*H_; tau += NB_) {
                int c = tau % NCH_, h = tau / NCH_;
                __syncthreads();
                if (t < 32) {
                    float pos = (float)(*p.pos);
                    float inv = expf(-(float)t * (9.210340371976184f / 32.0f));
                    float ang = pos * inv;
                    float cs = cosf(ang), sn = sinf(ang);
                    float q1 = p.accQKV[h*64 + t], q2 = p.accQKV[h*64 + t + 32];
                    qr[t] = q1*cs - q2*sn; qr[t+32] = q1*sn + q2*cs;
                    float k1 = p.accQKV[1024 + h*64 + t], k2 = p.accQKV[1024 + h*64 + t + 32];
                    kr[t] = k1*cs - k2*sn; kr[t+32] = k1*sn + k2*cs;
                }
                __syncthreads();
                int kstart = c * CHUNK_;
                int nk = min(CHUNK_, TC_ - kstart);
                // pass A: scores (16 lanes/key) + f32 K copy
                int dsub = (t & 15) * 4;
                float4 qv = *(const float4*)&qr[dsub];
                for (int kl = (t >> 4); kl < nk; kl += 16) {
                    int key = kstart + kl;
                    float4 kv;
                    if (key < T_) kv = *(const float4*)(kcache + ((size_t)h*T_ + key)*HD_ + dsub);
                    else          kv = *(const float4*)&kr[dsub];
                    float pd = qv.x*kv.x + qv.y*kv.y + qv.z*kv.z + qv.w*kv.w;
                    pd += __shfl_down(pd, 8, 16);
                    pd += __shfl_down(pd, 4, 16);
                    pd += __shfl_down(pd, 2, 16);
                    pd += __shfl_down(pd, 1, 16);
                    if ((t & 15) == 0) sc[kl] = pd * 0.125f;
                    *(float4*)(kco + ((size_t)h*TC_ + key)*HD_ + dsub) = kv;
                }
                __syncthreads();
                // parallel softmax (nk <= 64 <= 256: one element per thread)
                float m = (t < nk) ? sc[t] : -INFINITY;
                m = wave_max(m);
                if ((t & 63) == 0) wr2[t >> 6] = m;
                __syncthreads();
                m = fmaxf(fmaxf(wr2[0], wr2[1]), fmaxf(wr2[2], wr2[3]));
                float e = 0.f;
                if (t < nk) { e = __expf(sc[t] - m); sc[t] = e; }
                float s = wave_sum(e);
                if ((t & 63) == 0) wr2[4 + (t >> 6)] = s;
                __syncthreads();
                float stot = wr2[4] + wr2[5] + wr2[6] + wr2[7];
                float* pb = p.part + ((size_t)h*NCH_ + c)*66;
                if (t == 0) { pb[0] = m; pb[1] = stot; }
                __syncthreads();
                // pass B: weighted V + f32 V copy (dim = t&63, 4 key groups of 16)
                int dim = t & 63, kg = t >> 6;
                float acc = 0.f;
                int klend = min(nk, kg*16 + 16);
                for (int kl = kg*16; kl < klend; ++kl) {
                    int key = kstart + kl;
                    float v;
                    if (key < T_) v = vcache[((size_t)h*T_ + key)*HD_ + dim];
                    else          v = p.accQKV[2048 + h*64 + dim];
                    acc += sc[kl] * v;
                    vco[((size_t)h*TC_ + key)*HD_ + dim] = v;
                }
                red[t] = acc;
                __syncthreads();
                if (t < 64) pb[2 + t] = red[t] + red[t+64] + red[t+128] + red[t+192];
            }
        }
        grid.sync();

        // ======== phase 3: combine + Wo (16 heads x 16 coltiles = 256 tiles); zero accums ========
        {
            float* oh = sm;  // [64]
            for (int tau = b; tau < 256; tau += NB_) {
                int h = tau >> 4, ct = tau & 15;
                if (t < 64) {
                    const float* pb = p.part + (size_t)h * NCH_ * 66;
                    float M = -INFINITY;
                    for (int c = 0; c < NCH_; ++c) M = fmaxf(M, pb[c*66]);
                    float S = 0.f, O = 0.f;
                    for (int c = 0; c < NCH_; ++c) {
                        float e = __expf(pb[c*66] - M);
                        S += pb[c*66 + 1] * e;
                        O += pb[c*66 + 2 + t] * e;
                    }
                    oh[t] = O / S;
                }
                __syncthreads();
                gemv_tile<64>(oh - h*64, p.Wo + (size_t)L*D_*D_, D_, h*64, ct*64, SCALE_, p.hid, red4, t);
            }
            if (b == 256) for (int i = t; i < 2*FF_; i += 256) p.accGU[i] = 0.f;
            if (b == 257) for (int i = t; i < 3072; i += 256) p.accQKV[i] = 0.f;
        }
        grid.sync();

        // ======== phase 4: G/U gemv (2 x 8 rowtiles(128) x 64 coltiles = 1024 tiles) ========
        rms_to_sm(p.hid, p.ln2 + L*D_, hn, wred, t);
        for (int tau = b; tau < 1024; tau += NB_) {
            int mat = tau >> 9, rem = tau & 511, rt = rem >> 6, ct = rem & 63;
            const float* W = (mat ? p.Wu : p.Wg) + (size_t)L*D_*FF_;
            gemv_tile<128>(hn, W, FF_, rt*128, ct*64, 1.f, p.accGU + mat*FF_, red4, t);
        }
        grid.sync();

        // ======== phase 5: down gemv (64 rowtiles(64) x 16 coltiles = 1024 tiles) ========
        {
            float* act = sm;  // [64]
            for (int tau = b; tau < 1024; tau += NB_) {
                int rt = tau >> 4, ct = tau & 15;
                int rowbase = rt * 64;
                __syncthreads();
                if (t < 64) {
                    float g = p.accGU[rowbase + t];
                    float u = p.accGU[FF_ + rowbase + t];
                    act[t] = g / (1.f + __expf(-g)) * u;
                }
                __syncthreads();
                gemv_tile<64>(act - rowbase, p.Wd + (size_t)L*FF_*D_, D_, rowbase, ct*64, SCALE_, p.hid, red4, t);
            }
        }
        grid.sync();
    }

    // ======== final RMS norm ========
    if (b == 0) {
        float4 hv = ((const float4*)p.hid)[t];
        float ssq = hv.x*hv.x + hv.y*hv.y + hv.z*hv.z + hv.w*hv.w;
        ssq = wave_sum(ssq);
        if ((t & 63) == 0) wred[t >> 6] = ssq;
        __syncthreads();
        float rms = rsqrtf((wred[0] + wred[1] + wred[2] + wred[3]) * (1.0f / D_) + EPS_);
        float4 w = ((const float4*)p.nw)[t];
        float4 ob;
        ob.x = hv.x * rms * w.x; ob.y = hv.y * rms * w.y;
        ob.z = hv.z * rms * w.z; ob.w = hv.w * rms * w.w;
        ((float4*)p.out)[t] = ob;
    }
}

// ==================== fallback multi-kernel path (round-5, proven) ====================

__global__ void k_init(const float* __restrict__ embed, float* __restrict__ hid,
                       float* __restrict__ accQKV) {
    int t = threadIdx.x;
    ((float4*)hid)[t] = ((const float4*)embed)[t];
    for (int i = t; i < 3072; i += 256) accQKV[i] = 0.f;
}

template<int NCOLS>
__global__ void k_rms_gemv(const float* __restrict__ hidden, const float* __restrict__ lnw,
                           const float* __restrict__ W0, const float* __restrict__ W1,
                           const float* __restrict__ W2, float* __restrict__ out)
{
    int t = threadIdx.x;
    __shared__ float hn[D_];
    __shared__ float wred[4];
    __shared__ float4 red4s[256];
    rms_to_sm(hidden, lnw, hn, wred, t);
    const float* W = (blockIdx.z == 0) ? W0 : (blockIdx.z == 1 ? W1 : W2);
    gemv_tile<64>(hn, W, NCOLS, blockIdx.y*64, blockIdx.x*64, 1.f,
                  out + (size_t)blockIdx.z * NCOLS, red4s, t);
}

__global__ void k_attn_f(const float* __restrict__ kcache, const float* __restrict__ vcache,
                         const float* __restrict__ qkv, const int* __restrict__ posp,
                         float* __restrict__ kc_out, float* __restrict__ vc_out,
                         float* __restrict__ part)
{
    int c = blockIdx.x, h = blockIdx.y, t = threadIdx.x;
    __shared__ float qr[64], kr[64], sc[CHUNK_], red[256], wr2[8];
    if (t < 32) {
        float pos = (float)(*posp);
        float inv = expf(-(float)t * (9.210340371976184f / 32.0f));
        float ang = pos * inv;
        float cs = cosf(ang), sn = sinf(ang);
        float q1 = qkv[h*64 + t], q2 = qkv[h*64 + t + 32];
        qr[t] = q1*cs - q2*sn; qr[t+32] = q1*sn + q2*cs;
        float k1 = qkv[1024 + h*64 + t], k2 = qkv[1024 + h*64 + t + 32];
        kr[t] = k1*cs - k2*sn; kr[t+32] = k1*sn + k2*cs;
    }
    __syncthreads();
    int kstart = c * CHUNK_;
    int nk = min(CHUNK_, TC_ - kstart);
    int dsub = (t & 15) * 4;
    float4 qv = *(const float4*)&qr[dsub];
    for (int kl = (t >> 4); kl < nk; kl += 16) {
        int key = kstart + kl;
        float4 kv;
        if (key < T_) kv = *(const float4*)(kcache + ((size_t)h*T_ + key)*HD_ + dsub);
        else          kv = *(const float4*)&kr[dsub];
        float pd = qv.x*kv.x + qv.y*kv.y + qv.z*kv.z + qv.w*kv.w;
        pd += __shfl_down(pd, 8, 16);
        pd += __shfl_down(pd, 4, 16);
        pd += __shfl_down(pd, 2, 16);
        pd += __shfl_down(pd, 1, 16);
        if ((t & 15) == 0) sc[kl] = pd * 0.125f;
        *(float4*)(kc_out + ((size_t)h*TC_ + key)*HD_ + dsub) = kv;
    }
    __syncthreads();
    float m = (t < nk) ? sc[t] : -INFINITY;
    m = wave_max(m);
    if ((t & 63) == 0) wr2[t >> 6] = m;
    __syncthreads();
    m = fmaxf(fmaxf(wr2[0], wr2[1]), fmaxf(wr2[2], wr2[3]));
    float e = 0.f;
    if (t < nk) { e = __expf(sc[t] - m); sc[t] = e; }
    float s = wave_sum(e);
    if ((t & 63) == 0) wr2[4 + (t >> 6)] = s;
    __syncthreads();
    float* pb = part + ((size_t)h*NCH_ + c)*66;
    if (t == 0) { pb[0] = m; pb[1] = wr2[4]+wr2[5]+wr2[6]+wr2[7]; }
    __syncthreads();
    int dim = t & 63, kg = t >> 6;
    float acc = 0.f;
    int klend = min(nk, kg*16 + 16);
    for (int kl = kg*16; kl < klend; ++kl) {
        int key = kstart + kl;
        float v;
        if (key < T_) v = vcache[((size_t)h*T_ + key)*HD_ + dim];
        else          v = qkv[2048 + h*64 + dim];
        acc += sc[kl] * v;
        vc_out[((size_t)h*TC_ + key)*HD_ + dim] = v;
    }
    red[t] = acc;
    __syncthreads();
    if (t < 64) pb[2 + t] = red[t] + red[t+64] + red[t+128] + red[t+192];
}

__global__ void k_wo(const float* __restrict__ part, const float* __restrict__ Wo,
                     float* __restrict__ hidden, float* __restrict__ accGU)
{
    int h = blockIdx.y, t = threadIdx.x;
    if (blockIdx.x == 0 && blockIdx.y == 0)
        for (int i = t; i < 2*FF_; i += 256) accGU[i] = 0.f;
    __shared__ float oh[64];
    __shared__ float4 red4s[256];
    if (t < 64) {
        const float* pb = part + (size_t)h * NCH_ * 66;
        float M = -INFINITY;
        for (int c = 0; c < NCH_; ++c) M = fmaxf(M, pb[c*66]);
        float S = 0.f, O = 0.f;
        for (int c = 0; c < NCH_; ++c) {
            float e = __expf(pb[c*66] - M);
            S += pb[c*66 + 1] * e;
            O += pb[c*66 + 2 + t] * e;
        }
        oh[t] = O / S;
    }
    __syncthreads();
    gemv_tile<64>(oh - h*64, Wo, D_, h*64, blockIdx.x*64, SCALE_, hidden, red4s, t);
}

__global__ void k_down(const float* __restrict__ gu, const float* __restrict__ Wd,
                       float* __restrict__ hidden, float* __restrict__ accQKV)
{
    int t = threadIdx.x;
    if (blockIdx.x == 0 && blockIdx.y == 0)
        for (int i = t; i < 3072; i += 256) accQKV[i] = 0.f;
    __shared__ float act[64];
    __shared__ float4 red4s[256];
    int rowbase = blockIdx.y * 64;
    if (t < 64) {
        float g = gu[rowbase + t];
        float u = gu[FF_ + rowbase + t];
        act[t] = g / (1.f + __expf(-g)) * u;
    }
    __syncthreads();
    gemv_tile<64>(act - rowbase, Wd, D_, rowbase, blockIdx.x*64, SCALE_, hidden, red4s, t);
}

__global__ void k_final(const float* __restrict__ hidden, const float* __restrict__ nw,
                        float* __restrict__ out)
{
    int t = threadIdx.x;
    __shared__ float wred[4];
    float4 hv = ((const float4*)hidden)[t];
    float ssq = hv.x*hv.x + hv.y*hv.y + hv.z*hv.z + hv.w*hv.w;
    ssq = wave_sum(ssq);
    if ((t & 63) == 0) wred[t >> 6] = ssq;
    __syncthreads();
    float rms = rsqrtf((wred[0] + wred[1] + wred[2] + wred[3]) * (1.0f / D_) + EPS_);
    float4 w = ((const float4*)nw)[t];
    float4 ob;
    ob.x = hv.x * rms * w.x; ob.y = hv.y * rms * w.y;
    ob.z = hv.z * rms * w.z; ob.w = hv.w * rms * w.w;
    ((float4*)out)[t] = ob;
}

// role indices: 0 embed, 1+2i k_i, 2+2i v_i, 17 ln1, 18 ln2, 19 norm,
//               20 Wq, 21 Wk, 22 Wv, 23 Wo, 24 Wg, 25 Wu, 26 Wd, 27 pos
static const int ROLE_SIZES[28] = {
    1024,
    4194304,4194304,4194304,4194304,4194304,4194304,4194304,4194304,
    4194304,4194304,4194304,4194304,4194304,4194304,4194304,4194304,
    8192, 8192, 1024,
    8388608, 8388608, 8388608, 8388608,
    33554432, 33554432, 33554432,
    1
};

extern "C" void kernel_launch(void* const* d_in, const int* in_sizes, int n_in,
                              void* d_out, int out_size, void* d_ws, size_t ws_size,
                              hipStream_t stream)
{
    int perm[28];
    bool matched = false;
    auto try_perm = [&](const int* cand) {
        if (matched) return;
        for (int r = 0; r < 28; ++r)
            if (in_sizes[cand[r]] != ROLE_SIZES[r]) return;
        for (int r = 0; r < 28; ++r) perm[r] = cand[r];
        matched = true;
    };
    {   int c[28]; for (int r = 0; r < 28; ++r) c[r] = r; try_perm(c); }        // C0 dict (matched)
    {   int c[28];
        c[0]=0; c[27]=1;
        for (int i = 0; i < 8; ++i) { c[1+2*i]=2+2*i; c[2+2*i]=3+2*i; }
        c[17]=18; c[18]=19; c[19]=20;
        c[20]=21; c[21]=22; c[22]=23; c[23]=24; c[24]=25; c[25]=26; c[26]=27;
        try_perm(c); }                                                           // C1 signature
    if (!matched) { for (int r = 0; r < 28; ++r) perm[r] = r; }

    Params prm;
    prm.embed = (const float*)d_in[perm[0]];
    for (int i = 0; i < LAYERS_; ++i) {
        prm.kc[i] = (const float*)d_in[perm[1+2*i]];
        prm.vc[i] = (const float*)d_in[perm[2+2*i]];
    }
    prm.ln1 = (const float*)d_in[perm[17]];
    prm.ln2 = (const float*)d_in[perm[18]];
    prm.nw  = (const float*)d_in[perm[19]];
    prm.Wq  = (const float*)d_in[perm[20]];
    prm.Wk  = (const float*)d_in[perm[21]];
    prm.Wv  = (const float*)d_in[perm[22]];
    prm.Wo  = (const float*)d_in[perm[23]];
    prm.Wg  = (const float*)d_in[perm[24]];
    prm.Wu  = (const float*)d_in[perm[25]];
    prm.Wd  = (const float*)d_in[perm[26]];
    prm.pos = (const int*)d_in[perm[27]];

    float* ws = (float*)d_ws;
    prm.out    = (float*)d_out;
    prm.accQKV = ws + WS_QKV;
    prm.accGU  = ws + WS_GU;
    prm.hid    = ws + WS_HID;
    prm.part   = ws + WS_PART;

    (void)out_size; (void)ws_size; (void)n_in;

    void* kargs[] = { (void*)&prm };
    hipError_t err = hipLaunchCooperativeKernel((const void*)k_model, dim3(NB_), dim3(256),
                                                kargs, 0, stream);
    if (err == hipSuccess) return;

    // -------- fallback: proven multi-kernel path --------
    k_init<<<1, 256, 0, stream>>>(prm.embed, prm.hid, prm.accQKV);
    const size_t KVSZ = (size_t)H_ * TC_ * HD_;
    for (int i = 0; i < LAYERS_; ++i) {
        float* kco = prm.out + 1024 + (size_t)i * 2 * KVSZ;
        float* vco = kco + KVSZ;
        k_rms_gemv<D_><<<dim3(16, 16, 3), 256, 0, stream>>>(
            prm.hid, prm.ln1 + i*D_,
            prm.Wq + (size_t)i*D_*D_, prm.Wk + (size_t)i*D_*D_, prm.Wv + (size_t)i*D_*D_,
            prm.accQKV);
        k_attn_f<<<dim3(NCH_, H_), 256, 0, stream>>>(prm.kc[i], prm.vc[i], prm.accQKV, prm.pos,
                                                     kco, vco, prm.part);
        k_wo<<<dim3(16, 16), 256, 0, stream>>>(prm.part, prm.Wo + (size_t)i*D_*D_, prm.hid, prm.accGU);
        k_rms_gemv<FF_><<<dim3(64, 16, 2), 256, 0, stream>>>(
            prm.hid, prm.ln2 + i*D_,
            prm.Wg + (size_t)i*D_*FF_, prm.Wu + (size_t)i*D_*FF_, nullptr,
            prm.accGU);
        k_down<<<dim3(16, 64), 256, 0, stream>>>(prm.accGU, prm.Wd + (size_t)i*FF_*D_, prm.hid, prm.accQKV);
    }
    k_final<<<1, 256, 0, stream>>>(prm.hid, prm.nw, prm.out);
}